// Round 9
// baseline (213.860 us; speedup 1.0000x reference)
//
#include <hip/hip_runtime.h>

// Problem constants (fixed by setup_inputs)
constexpr int B = 4, Q = 100, C = 40, Cp1 = 41, HW = 65536;

// R7: async global->LDS staging. Same verified structure as R2/R5/R6 (512
// blocks x 256 thr, 2 px/thread, per-qt tile + one-hot MFMA), but the mask
// loads are global_load_lds DMA (1 KB/inst, no VGPR cost), issued ONE PHASE
// EARLY (before MFMA of the previous tile). R2-R6 all pinned at ~77us with
// compiler-batched VGPR loads (~4 deep) exposing ~900cy latency 3-4x per qt;
// this raises per-wave issue depth to 8x1KB with the latency hidden under
// MFMA + the co-resident block. __syncthreads drains vmcnt(0) (guide §5),
// so no inline-asm waits are needed.
constexpr int FBLKS = 512;

// Workspace layout (4-byte words):
//  [0, 16000)        counts    u32 [B][Q][C]
//  [16000, 16160)    tsum      u32 [B][C]
//  [16160]           ce_sum    f32
//  [16161]           n_valid   u32
//  [16162, 32562)    inter_ext f32 [B*Q][41]   (col 40 = ignored-pixel sig sum)
constexpr int WS_WORDS = 32562;

typedef __attribute__((ext_vector_type(8))) short short8;   // 8 bf16
typedef __attribute__((ext_vector_type(4))) float f32x4;

__device__ __forceinline__ short f2bf(float f) {            // RNE f32->bf16
    unsigned u = __float_as_uint(f);
    u += 0x7FFF + ((u >> 16) & 1);
    return (short)(u >> 16);
}

__device__ __forceinline__ void gload16(const void* g, void* l) {
    // DMA 64 lanes x 16B -> LDS[uniform base + lane*16]; counted in vmcnt.
    __builtin_amdgcn_global_load_lds(
        (const __attribute__((address_space(1))) unsigned*)g,
        (__attribute__((address_space(3))) unsigned*)l, 16, 0, 0);
}

__global__ void kZ(unsigned* __restrict__ ws, int n) {
    int i = blockIdx.x * blockDim.x + threadIdx.x;
    for (; i < n; i += gridDim.x * blockDim.x) ws[i] = 0u;
}

__global__ __launch_bounds__(256) void kF(const float* __restrict__ masks,
                                          const int* __restrict__ targets,
                                          unsigned* __restrict__ counts,
                                          unsigned* __restrict__ tsum,
                                          float* __restrict__ ce_sum,
                                          unsigned* __restrict__ n_valid,
                                          float* __restrict__ inter_ext) {
    // stageF: raw f32 plane chunks, LINEAR layout (global_load_lds rule:
    // dest = uniform base + lane*16; process reads are 2-way-bank, free).
    // tileS: bf16 sigmoid tile, swizzle byte ^= ((row&7)<<4) (verified R2).
    __shared__ __align__(16) float stageF[16 * 512];         // 32 KiB
    __shared__ __align__(16) short tileS[2][16 * 512];       // 2 x 16 KiB
    __shared__ __align__(8) unsigned char tgt8[512];
    __shared__ unsigned ts_local[C];
    __shared__ float cred[4];
    __shared__ unsigned vred[4];

    const int tid = threadIdx.x;            // 0..255
    const int l = tid & 63, w = tid >> 6;   // wave 0..3
    const int m = l & 15, quad = l >> 4;

    const int blk = blockIdx.x;
    const int b = blk >> 7;                 // 0..3
    const int seg = blk & 127;              // 0..127
    const int p0 = seg * 512 + 2 * tid;     // px within image (2 px/thread)

    // ---- prologue (LDS consumed only after the qt=0 barrier) ----
    const int2 tg = *(const int2*)(targets + (size_t)b * HW + p0);
    const int tg0 = tg.x, tg1 = tg.y;
    *(unsigned short*)&tgt8[2 * tid] =
        (unsigned short)((tg0 & 255) | ((tg1 & 255) << 8));
    if (tid < C) ts_local[tid] = 0u;

    const float* mseg = masks + (size_t)b * Q * HW + seg * 512;

    // STAGE(qt): wave w stages planes w*4..w*4+3 (512 px = 2 KB = 2 insts ea).
    // qt=6: only wave 0 (planes 96-99); guard prevents OOB reads past masks.
    auto STAGE = [&](int qt) {
        const int q0 = qt * 16 + w * 4;
        if (q0 < 100) {
            const float* pb = mseg + (size_t)q0 * HW;
            char* lb = (char*)stageF + (w * 4) * 2048;
            #pragma unroll
            for (int j = 0; j < 8; ++j) {
                const int u = j >> 1, half = j & 1;
                gload16(pb + (size_t)u * HW + half * 256 + l * 4,
                        lb + u * 2048 + half * 1024);
            }
        }
    };

    STAGE(0);                               // in flight across first barrier

    // per-pixel softmax state (2 px/thread) — formulas/order == verified R2
    float m20 = -INFINITY, m21 = -INFINITY;
    float s0 = 0.f, s1 = 0.f, xt0 = 0.f, xt1 = 0.f;
    int am0 = 0, am1 = 0;

    // wave MFMA role: w0 cols 0-15, w1 16-31, w2 32-40 (m>8 dead), w3 none
    const int cv = (w == 2 && m == 8) ? 255 : (w * 16 + m);

    for (int qt = 0; qt < 7; ++qt) {
        char* tbq = (char*)(&tileS[qt & 1][0]);
        const int nu = (qt == 6) ? 4 : 16;

        __syncthreads();   // drains vmcnt(0)+lgkmcnt(0): stage(qt) landed in
                           // ALL waves; also fences tgt8/ts_local at qt=0.

        // ---- process: read f32 from stage LDS; softmax + sigmoid tile ----
        #pragma unroll
        for (int u = 0; u < 16; ++u)
            if (u < nu) {
                const int q = qt * 16 + u;
                const float2 vp = *(const float2*)&stageF[u * 512 + 2 * tid];
                const float v0 = vp.x, v1 = vp.y;
                s0 += __expf(v0);
                s1 += __expf(v1);
                am0 = (v0 > m20) ? q : am0;  m20 = fmaxf(m20, v0);
                am1 = (v1 > m21) ? q : am1;  m21 = fmaxf(m21, v1);
                xt0 = (q == tg0) ? v0 : xt0;
                xt1 = (q == tg1) ? v1 : xt1;
                const float g0 = __builtin_amdgcn_rcpf(1.f + __expf(-v0));
                const float g1 = __builtin_amdgcn_rcpf(1.f + __expf(-v1));
                const unsigned pk = (unsigned)(unsigned short)f2bf(g0) |
                                    ((unsigned)(unsigned short)f2bf(g1) << 16);
                *(unsigned*)(tbq + ((u * 1024 + 4 * tid) ^ ((u & 7) << 4))) = pk;
            }

        __syncthreads();   // tile[qt&1] published; all waves done reading
                           // stageF -> safe to overwrite it via DMA below.

        if (qt < 6) STAGE(qt + 1);   // fire & forget; flies across MFMA and
                                     // is drained by the next top barrier.

        // ---- MFMA phase: one-hot GEMM, inputs bit-identical to R2/R5/R6 ----
        if (w < 3) {
            f32x4 acc = {0.f, 0.f, 0.f, 0.f};
            #pragma unroll
            for (int kc = 0; kc < 16; ++kc) {
                const short8 av = *(const short8*)(tbq +
                    ((m * 1024 + kc * 64 + quad * 16) ^ ((m & 7) << 4)));
                const unsigned long long tw =
                    *(const unsigned long long*)&tgt8[kc * 32 + quad * 8];
                short8 bv;
                #pragma unroll
                for (int j = 0; j < 8; ++j)
                    bv[j] = ((int)((tw >> (8 * j)) & 255) == cv)
                                ? (short)0x3F80 : (short)0;
                acc = __builtin_amdgcn_mfma_f32_16x16x32_bf16(av, bv, acc,
                                                              0, 0, 0);
            }
            // epilogue: D row = quad*4+reg (q), col = m (+16*w); global
            // atomics (R5-verified; keeps LDS <= 80KB for 2 blocks/CU).
            // qt=6 rows 4..15 are stale -> q>=100, skipped.
            if (!(w == 2 && m > 8)) {
                #pragma unroll
                for (int reg = 0; reg < 4; ++reg) {
                    const int q = qt * 16 + quad * 4 + reg;
                    if (q < 100)
                        atomicAdd(&inter_ext[(size_t)(b * Q + q) * Cp1 +
                                             w * 16 + m], acc[reg]);
                }
            }
        }
    }

    // ---- softmax epilogue (identical math to verified R2/R6) ----
    float ce = 0.f;
    unsigned nv = 0u;
    if (tg0 != 255) {
        ce += __logf(s0) - xt0; nv++;
        atomicAdd(&counts[((size_t)b * Q + am0) * C + tg0], 1u);
        atomicAdd(&ts_local[tg0], 1u);
    }
    if (tg1 != 255) {
        ce += __logf(s1) - xt1; nv++;
        atomicAdd(&counts[((size_t)b * Q + am1) * C + tg1], 1u);
        atomicAdd(&ts_local[tg1], 1u);
    }
    for (int off = 32; off; off >>= 1) {
        ce += __shfl_xor(ce, off);
        nv += __shfl_xor(nv, off);
    }
    if (l == 0) { cred[w] = ce; vred[w] = nv; }
    __syncthreads();
    if (tid == 0) {
        atomicAdd(ce_sum, cred[0] + cred[1] + cred[2] + cred[3]);
        atomicAdd(n_valid, vred[0] + vred[1] + vred[2] + vred[3]);
    }
    if (tid < C) {
        unsigned t = ts_local[tid];
        if (t) atomicAdd(&tsum[b * C + tid], t);
    }
}

// Kernel C: finalize (verified R6 1024-thread version).
__global__ __launch_bounds__(1024) void kC(const float* __restrict__ logits,
                                           const unsigned* __restrict__ counts,
                                           const unsigned* __restrict__ tsum,
                                           const float* __restrict__ inter_ext,
                                           const float* __restrict__ ce_sum,
                                           const unsigned* __restrict__ n_valid,
                                           float* __restrict__ out) {
    int tid = threadIdx.x;
    __shared__ float dice_sum[C];
    __shared__ float ssum[B * Q];
    __shared__ float wred[16];
    __shared__ float s_lce;
    if (tid < C) dice_sum[tid] = 0.f;
    if (tid < B * Q) {                     // src_sum[bq] = sum of all 41 cols
        const float* r = inter_ext + (size_t)tid * Cp1;
        float t = 0.f;
        #pragma unroll
        for (int c = 0; c < Cp1; ++c) t += r[c];
        ssum[tid] = t;
    }

    float ce_acc = 0.f;
    for (int i = tid; i < B * Q; i += 1024) {
        const unsigned* cnt = counts + (size_t)i * C;
        unsigned best = 0;
        int tc = C;
        #pragma unroll
        for (int c = 0; c < C; ++c) {
            unsigned v = cnt[c];
            if (v > best) { best = v; tc = c; }
        }
        if (tc != C) {
            const float* lg = logits + (size_t)i * Cp1;
            float mm = -INFINITY, xt = 0.f;
            #pragma unroll
            for (int c = 0; c < Cp1; ++c) {
                float v = lg[c];
                mm = fmaxf(mm, v);
                if (c == tc) xt = v;
            }
            float ss = 0.f;
            #pragma unroll
            for (int c = 0; c < Cp1; ++c) ss += __expf(lg[c] - mm);
            float nll = mm + __logf(ss) - xt;
            float p = __expf(-nll);
            float om = 1.f - p;
            ce_acc += om * om * nll;
        }
    }
    for (int off = 32; off; off >>= 1) ce_acc += __shfl_xor(ce_acc, off);
    if ((tid & 63) == 0) wred[tid >> 6] = ce_acc;
    __syncthreads();                        // also publishes ssum + dice_sum init
    if (tid == 0) {
        float t = 0.f;
        for (int w = 0; w < 16; ++w) t += wred[w];
        s_lce = t;
    }

    for (int i = tid; i < B * Q * C; i += 1024) {
        int bq = i / C, c = i - bq * C;
        float denom = ssum[bq] + (float)tsum[(bq / Q) * C + c] + 1e-8f;
        atomicAdd(&dice_sum[c], 2.f * inter_ext[(size_t)bq * Cp1 + c] / denom);
    }
    __syncthreads();

    if (tid == 0) {
        float dl = 0.f;
        for (int c = 0; c < C; ++c) {
            unsigned ts = tsum[c] + tsum[C + c] + tsum[2 * C + c] + tsum[3 * C + c];
            if (ts > 0) dl += 1.f - dice_sum[c] * (1.f / (B * Q));
        }
        dl *= (1.f / C);
        float ce_mask = ce_sum[0] / fmaxf((float)n_valid[0], 1.f);
        float lce = s_lce * (1.f / (B * Q));
        out[0] = 2.f * lce + 5.f * ce_mask + 5.f * dl;
    }
}

extern "C" void kernel_launch(void* const* d_in, const int* in_sizes, int n_in,
                              void* d_out, int out_size, void* d_ws, size_t ws_size,
                              hipStream_t stream) {
    const float* logits  = (const float*)d_in[0];   // [B,Q,41] f32
    const float* masks   = (const float*)d_in[1];   // [B,Q,H,W] f32
    const int*   targets = (const int*)d_in[2];     // [B,H,W] int32
    float* out = (float*)d_out;                     // f32 scalar

    unsigned* ws        = (unsigned*)d_ws;
    unsigned* counts    = ws;                       // 16000 u32
    unsigned* tsum      = ws + 16000;               // 160 u32
    float*    ce_sum    = (float*)(ws + 16160);     // 1 f32
    unsigned* n_valid   = ws + 16161;               // 1 u32
    float*    inter_ext = (float*)(ws + 16162);     // 16400 f32

    kZ<<<64, 256, 0, stream>>>(ws, WS_WORDS);
    kF<<<FBLKS, 256, 0, stream>>>(masks, targets, counts, tsum, ce_sum, n_valid,
                                  inter_ext);
    kC<<<1, 1024, 0, stream>>>(logits, counts, tsum, inter_ext, ce_sum, n_valid, out);
}

// Round 10
// 197.968 us; speedup vs baseline: 1.0803x; 1.0803x over previous
//
#include <hip/hip_runtime.h>

// Problem constants (fixed by setup_inputs)
constexpr int B = 4, Q = 100, C = 40, Cp1 = 41, HW = 65536;

// kF: R7 verified (75.7us): async global->LDS staging, 512 blocks x 256 thr.
// R8 change is OUTSIDE kF: the single-block kC (est. tens of us on 1 CU) is
// split into kCrow (400 blocks x 1 wave, one per (b,q) row, lane-parallel
// over classes) + kCfin (1 tiny block). kF frozen for single-variable A/B.
constexpr int FBLKS = 512;

// Workspace layout (4-byte words):
//  [0, 16000)        counts    u32 [B][Q][C]
//  [16000, 16160)    tsum      u32 [B][C]
//  [16160]           ce_sum    f32
//  [16161]           n_valid   u32
//  [16162, 32562)    inter_ext f32 [B*Q][41]   (col 40 = ignored-pixel sig sum)
//  [32562, 32602)    dice_g    f32 [C]
//  [32602]           lce_acc   f32
constexpr int WS_WORDS = 32603;

typedef __attribute__((ext_vector_type(8))) short short8;   // 8 bf16
typedef __attribute__((ext_vector_type(4))) float f32x4;

__device__ __forceinline__ short f2bf(float f) {            // RNE f32->bf16
    unsigned u = __float_as_uint(f);
    u += 0x7FFF + ((u >> 16) & 1);
    return (short)(u >> 16);
}

__device__ __forceinline__ void gload16(const void* g, void* l) {
    // DMA 64 lanes x 16B -> LDS[uniform base + lane*16]; counted in vmcnt.
    __builtin_amdgcn_global_load_lds(
        (const __attribute__((address_space(1))) unsigned*)g,
        (__attribute__((address_space(3))) unsigned*)l, 16, 0, 0);
}

__global__ void kZ(unsigned* __restrict__ ws, int n) {
    int i = blockIdx.x * blockDim.x + threadIdx.x;
    for (; i < n; i += gridDim.x * blockDim.x) ws[i] = 0u;
}

__global__ __launch_bounds__(256) void kF(const float* __restrict__ masks,
                                          const int* __restrict__ targets,
                                          unsigned* __restrict__ counts,
                                          unsigned* __restrict__ tsum,
                                          float* __restrict__ ce_sum,
                                          unsigned* __restrict__ n_valid,
                                          float* __restrict__ inter_ext) {
    // stageF: raw f32 plane chunks, LINEAR layout (global_load_lds rule:
    // dest = uniform base + lane*16; process reads are 2-way-bank, free).
    // tileS: bf16 sigmoid tile, swizzle byte ^= ((row&7)<<4) (verified R2).
    __shared__ __align__(16) float stageF[16 * 512];         // 32 KiB
    __shared__ __align__(16) short tileS[2][16 * 512];       // 2 x 16 KiB
    __shared__ __align__(8) unsigned char tgt8[512];
    __shared__ unsigned ts_local[C];
    __shared__ float cred[4];
    __shared__ unsigned vred[4];

    const int tid = threadIdx.x;            // 0..255
    const int l = tid & 63, w = tid >> 6;   // wave 0..3
    const int m = l & 15, quad = l >> 4;

    const int blk = blockIdx.x;
    const int b = blk >> 7;                 // 0..3
    const int seg = blk & 127;              // 0..127
    const int p0 = seg * 512 + 2 * tid;     // px within image (2 px/thread)

    // ---- prologue (LDS consumed only after the qt=0 barrier) ----
    const int2 tg = *(const int2*)(targets + (size_t)b * HW + p0);
    const int tg0 = tg.x, tg1 = tg.y;
    *(unsigned short*)&tgt8[2 * tid] =
        (unsigned short)((tg0 & 255) | ((tg1 & 255) << 8));
    if (tid < C) ts_local[tid] = 0u;

    const float* mseg = masks + (size_t)b * Q * HW + seg * 512;

    // STAGE(qt): wave w stages planes w*4..w*4+3 (512 px = 2 KB = 2 insts ea).
    // qt=6: only wave 0 (planes 96-99); guard prevents OOB reads past masks.
    auto STAGE = [&](int qt) {
        const int q0 = qt * 16 + w * 4;
        if (q0 < 100) {
            const float* pb = mseg + (size_t)q0 * HW;
            char* lb = (char*)stageF + (w * 4) * 2048;
            #pragma unroll
            for (int j = 0; j < 8; ++j) {
                const int u = j >> 1, half = j & 1;
                gload16(pb + (size_t)u * HW + half * 256 + l * 4,
                        lb + u * 2048 + half * 1024);
            }
        }
    };

    STAGE(0);                               // in flight across first barrier

    // per-pixel softmax state (2 px/thread) — formulas/order == verified R2
    float m20 = -INFINITY, m21 = -INFINITY;
    float s0 = 0.f, s1 = 0.f, xt0 = 0.f, xt1 = 0.f;
    int am0 = 0, am1 = 0;

    // wave MFMA role: w0 cols 0-15, w1 16-31, w2 32-40 (m>8 dead), w3 none
    const int cv = (w == 2 && m == 8) ? 255 : (w * 16 + m);

    for (int qt = 0; qt < 7; ++qt) {
        char* tbq = (char*)(&tileS[qt & 1][0]);
        const int nu = (qt == 6) ? 4 : 16;

        __syncthreads();   // drains vmcnt(0)+lgkmcnt(0): stage(qt) landed in
                           // ALL waves; also fences tgt8/ts_local at qt=0.

        // ---- process: read f32 from stage LDS; softmax + sigmoid tile ----
        #pragma unroll
        for (int u = 0; u < 16; ++u)
            if (u < nu) {
                const int q = qt * 16 + u;
                const float2 vp = *(const float2*)&stageF[u * 512 + 2 * tid];
                const float v0 = vp.x, v1 = vp.y;
                s0 += __expf(v0);
                s1 += __expf(v1);
                am0 = (v0 > m20) ? q : am0;  m20 = fmaxf(m20, v0);
                am1 = (v1 > m21) ? q : am1;  m21 = fmaxf(m21, v1);
                xt0 = (q == tg0) ? v0 : xt0;
                xt1 = (q == tg1) ? v1 : xt1;
                const float g0 = __builtin_amdgcn_rcpf(1.f + __expf(-v0));
                const float g1 = __builtin_amdgcn_rcpf(1.f + __expf(-v1));
                const unsigned pk = (unsigned)(unsigned short)f2bf(g0) |
                                    ((unsigned)(unsigned short)f2bf(g1) << 16);
                *(unsigned*)(tbq + ((u * 1024 + 4 * tid) ^ ((u & 7) << 4))) = pk;
            }

        __syncthreads();   // tile[qt&1] published; all waves done reading
                           // stageF -> safe to overwrite it via DMA below.

        if (qt < 6) STAGE(qt + 1);   // fire & forget; flies across MFMA and
                                     // is drained by the next top barrier.

        // ---- MFMA phase: one-hot GEMM, inputs bit-identical to R2/R5/R6 ----
        if (w < 3) {
            f32x4 acc = {0.f, 0.f, 0.f, 0.f};
            #pragma unroll
            for (int kc = 0; kc < 16; ++kc) {
                const short8 av = *(const short8*)(tbq +
                    ((m * 1024 + kc * 64 + quad * 16) ^ ((m & 7) << 4)));
                const unsigned long long tw =
                    *(const unsigned long long*)&tgt8[kc * 32 + quad * 8];
                short8 bv;
                #pragma unroll
                for (int j = 0; j < 8; ++j)
                    bv[j] = ((int)((tw >> (8 * j)) & 255) == cv)
                                ? (short)0x3F80 : (short)0;
                acc = __builtin_amdgcn_mfma_f32_16x16x32_bf16(av, bv, acc,
                                                              0, 0, 0);
            }
            // epilogue: D row = quad*4+reg (q), col = m (+16*w).
            // qt=6 rows 4..15 are stale -> q>=100, skipped.
            if (!(w == 2 && m > 8)) {
                #pragma unroll
                for (int reg = 0; reg < 4; ++reg) {
                    const int q = qt * 16 + quad * 4 + reg;
                    if (q < 100)
                        atomicAdd(&inter_ext[(size_t)(b * Q + q) * Cp1 +
                                             w * 16 + m], acc[reg]);
                }
            }
        }
    }

    // ---- softmax epilogue (identical math to verified R2/R6) ----
    float ce = 0.f;
    unsigned nv = 0u;
    if (tg0 != 255) {
        ce += __logf(s0) - xt0; nv++;
        atomicAdd(&counts[((size_t)b * Q + am0) * C + tg0], 1u);
        atomicAdd(&ts_local[tg0], 1u);
    }
    if (tg1 != 255) {
        ce += __logf(s1) - xt1; nv++;
        atomicAdd(&counts[((size_t)b * Q + am1) * C + tg1], 1u);
        atomicAdd(&ts_local[tg1], 1u);
    }
    for (int off = 32; off; off >>= 1) {
        ce += __shfl_xor(ce, off);
        nv += __shfl_xor(nv, off);
    }
    if (l == 0) { cred[w] = ce; vred[w] = nv; }
    __syncthreads();
    if (tid == 0) {
        atomicAdd(ce_sum, cred[0] + cred[1] + cred[2] + cred[3]);
        atomicAdd(n_valid, vred[0] + vred[1] + vred[2] + vred[3]);
    }
    if (tid < C) {
        unsigned t = ts_local[tid];
        if (t) atomicAdd(&tsum[b * C + tid], t);
    }
}

// kCrow: one wave per (b,q) row. Lane-parallel over classes; shfl-tree
// reductions; dice + focal-CE partials accumulated via global f32 atomics
// (same risk class as ce_sum accumulation, verified absmax=0.0 in R1-R7).
__global__ __launch_bounds__(64) void kCrow(const float* __restrict__ logits,
                                            const unsigned* __restrict__ counts,
                                            const unsigned* __restrict__ tsum,
                                            const float* __restrict__ inter_ext,
                                            float* __restrict__ dice_g,
                                            float* __restrict__ lce_acc) {
    const int bq = blockIdx.x;              // 0..399
    const int b = bq / Q;
    const int l = threadIdx.x;              // 0..63

    // ---- dice: ssum = sum of 41 inter cols; per-class term ----
    const float iv = (l < Cp1) ? inter_ext[(size_t)bq * Cp1 + l] : 0.f;
    float ssum = iv;
    #pragma unroll
    for (int off = 32; off; off >>= 1) ssum += __shfl_xor(ssum, off);
    if (l < C) {
        const float denom = ssum + (float)tsum[b * C + l] + 1e-8f;
        atomicAdd(&dice_g[l], 2.f * iv / denom);
    }

    // ---- counts argmax (strict >, first index wins ties) ----
    const unsigned v = (l < C) ? counts[(size_t)bq * C + l] : 0u;
    unsigned mx = v;
    #pragma unroll
    for (int off = 32; off; off >>= 1) {
        const unsigned o = __shfl_xor(mx, off);
        mx = (o > mx) ? o : mx;
    }
    int cand = (v == mx) ? l : 64;
    #pragma unroll
    for (int off = 32; off; off >>= 1) {
        const int o = __shfl_xor(cand, off);
        cand = (o < cand) ? o : cand;
    }

    // ---- focal CE for this row (skip if no pixels: mx==0 -> tc==C) ----
    if (mx != 0u) {
        const int tc = cand;
        const float x = (l < Cp1) ? logits[(size_t)bq * Cp1 + l] : -INFINITY;
        float mm = x;
        #pragma unroll
        for (int off = 32; off; off >>= 1) mm = fmaxf(mm, __shfl_xor(mm, off));
        float ss = (l < Cp1) ? __expf(x - mm) : 0.f;
        #pragma unroll
        for (int off = 32; off; off >>= 1) ss += __shfl_xor(ss, off);
        const float xt = __shfl(x, tc);
        if (l == 0) {
            const float nll = mm + __logf(ss) - xt;
            const float p = __expf(-nll);
            const float om = 1.f - p;
            atomicAdd(lce_acc, om * om * nll);
        }
    }
}

// kCfin: scalar combine (1 wave).
__global__ __launch_bounds__(64) void kCfin(const unsigned* __restrict__ tsum,
                                            const float* __restrict__ dice_g,
                                            const float* __restrict__ ce_sum,
                                            const unsigned* __restrict__ n_valid,
                                            const float* __restrict__ lce_acc,
                                            float* __restrict__ out) {
    const int l = threadIdx.x;
    float dterm = 0.f;
    if (l < C) {
        const unsigned ts = tsum[l] + tsum[C + l] + tsum[2 * C + l] +
                            tsum[3 * C + l];
        if (ts > 0) dterm = 1.f - dice_g[l] * (1.f / (B * Q));
    }
    #pragma unroll
    for (int off = 32; off; off >>= 1) dterm += __shfl_xor(dterm, off);
    if (l == 0) {
        const float dl = dterm * (1.f / C);
        const float ce_mask = ce_sum[0] / fmaxf((float)n_valid[0], 1.f);
        const float lce = lce_acc[0] * (1.f / (B * Q));
        out[0] = 2.f * lce + 5.f * ce_mask + 5.f * dl;
    }
}

extern "C" void kernel_launch(void* const* d_in, const int* in_sizes, int n_in,
                              void* d_out, int out_size, void* d_ws, size_t ws_size,
                              hipStream_t stream) {
    const float* logits  = (const float*)d_in[0];   // [B,Q,41] f32
    const float* masks   = (const float*)d_in[1];   // [B,Q,H,W] f32
    const int*   targets = (const int*)d_in[2];     // [B,H,W] int32
    float* out = (float*)d_out;                     // f32 scalar

    unsigned* ws        = (unsigned*)d_ws;
    unsigned* counts    = ws;                       // 16000 u32
    unsigned* tsum      = ws + 16000;               // 160 u32
    float*    ce_sum    = (float*)(ws + 16160);     // 1 f32
    unsigned* n_valid   = ws + 16161;               // 1 u32
    float*    inter_ext = (float*)(ws + 16162);     // 16400 f32
    float*    dice_g    = (float*)(ws + 32562);     // 40 f32
    float*    lce_acc   = (float*)(ws + 32602);     // 1 f32

    kZ<<<64, 256, 0, stream>>>(ws, WS_WORDS);
    kF<<<FBLKS, 256, 0, stream>>>(masks, targets, counts, tsum, ce_sum, n_valid,
                                  inter_ext);
    kCrow<<<B * Q, 64, 0, stream>>>(logits, counts, tsum, inter_ext, dice_g,
                                    lce_acc);
    kCfin<<<1, 64, 0, stream>>>(tsum, dice_g, ce_sum, n_valid, lce_acc, out);
}